// Round 12
// baseline (153.565 us; speedup 1.0000x reference)
//
#include <hip/hip_runtime.h>

#define BB 2
#define HH 1024
#define WW 1024
#define MU 5
#define VSTRIP 8

__device__ __forceinline__ float fast_rcp(float x) { return __builtin_amdgcn_rcpf(x); }
__device__ __forceinline__ float fast_rsq(float x) { return __builtin_amdgcn_rsqf(x); }

// ---------------------------------------------------------------------------
// Kernel 1: Sobel + init tangent ((B,H,W) float2) + raw mag + per-block max.
// (R7/R11-proven; no atomics, no fences.)
// ---------------------------------------------------------------------------
#define SR 8
__global__ __launch_bounds__(256) void sobel_init(
    const float* __restrict__ x,
    float2* __restrict__ tf,
    float* __restrict__ mag,
    float* __restrict__ block_max)   // 1024
{
    __shared__ float xs[SR + 2][264];
    const int t = threadIdx.x;
    const int w0 = blockIdx.x * 256;
    const int h0 = blockIdx.y * SR;
    const int b = blockIdx.z;
    const size_t plane = (size_t)HH * WW;
    const float* xb = x + (size_t)b * plane;

    for (int i = t; i < (SR + 2) * 66; i += 256) {
        int r = i / 66, c4 = i % 66;
        int g = h0 - 1 + r;
        int gw = w0 - 4 + 4 * c4;
        float4 v = make_float4(0.f, 0.f, 0.f, 0.f);
        if (g >= 0 && g < HH && gw >= 0 && gw < WW)
            v = *(const float4*)(xb + (size_t)g * WW + gw);
        *(float4*)&xs[r][4 * c4] = v;
    }
    __syncthreads();

    float lmax = 0.f;
    const int c = 4 + t;
    #pragma unroll
    for (int k = 0; k < SR; ++k) {
        const float* rT = xs[k], * rM = xs[k + 1], * rB = xs[k + 2];
        float tl = rT[c - 1], tc = rT[c], tr = rT[c + 1];
        float ml = rM[c - 1],             mr = rM[c + 1];
        float bl = rB[c - 1], bc = rB[c], br = rB[c + 1];
        float s0 = (bl - tl) + 2.f * (bc - tc) + (br - tr);   // k
        float s1 = (tr - tl) + 2.f * (mr - ml) + (br - bl);   // k^T
        float m = sqrtf(fmaf(s0, s0, s1 * s1));
        float inv = (m == 0.f) ? 1.f : fast_rcp(m);
        size_t gi = (size_t)(h0 + k) * WW + (w0 + t);
        mag[(size_t)b * plane + gi] = m;
        tf[(size_t)b * plane + gi] = make_float2(-s1 * inv, s0 * inv);
        lmax = fmaxf(lmax, m);
    }

    #pragma unroll
    for (int off = 32; off; off >>= 1) lmax = fmaxf(lmax, __shfl_down(lmax, off, 64));
    __shared__ float smax[4];
    if ((t & 63) == 0) smax[t >> 6] = lmax;
    __syncthreads();
    if (t == 0)
        block_max[(blockIdx.z * 128 + blockIdx.y) * 4 + blockIdx.x] =
            fmaxf(fmaxf(smax[0], smax[1]), fmaxf(smax[2], smax[3]));
}

// redundant per-block gmax reduce (proven ~free in R11); returns s2 = 2/gmax
__device__ __forceinline__ float gmax_prologue(const float* __restrict__ block_max,
                                               int t, float* smax)
{
    float m = fmaxf(fmaxf(block_max[t], block_max[t + 256]),
                    fmaxf(block_max[t + 512], block_max[t + 768]));
    #pragma unroll
    for (int off = 32; off; off >>= 1) m = fmaxf(m, __shfl_down(m, off, 64));
    if ((t & 63) == 0) smax[t >> 6] = m;
    __syncthreads();
    float gm = fmaxf(fmaxf(smax[0], smax[1]), fmaxf(smax[2], smax[3]));
    return 2.f * fast_rcp(gm);
}

// ---------------------------------------------------------------------------
// Kernel 2: VERTICAL pass — no LDS staging, no compute barriers. Thread owns
// an 8-row column strip; 18-row register window loaded coalesced from global
// (lane = col). em computed on the fly: em=exp(-2*mag/max); weight identity
// (tanh(my-mx)+1)/2 == 1/(1+em_y/em_x). OOB: tang=0, em=exp(0)=1 (exact
// reference zero-pad; normalize(0)=0 matches the mag==0 guard).
// No LDS -> ~6 blocks/CU resident: deep latency hiding (R11 lesson: the fused
// kernel's barriers phase-locked the CU).
// ---------------------------------------------------------------------------
__global__ __launch_bounds__(256) void etf_v(
    const float2* __restrict__ tin, float2* __restrict__ tout,
    const float* __restrict__ mag, const float* __restrict__ block_max)
{
    __shared__ float smax[4];
    const int t = threadIdx.x;
    const float s2 = gmax_prologue(block_max, t, smax);

    const int c  = blockIdx.x * 256 + t;
    const int r0 = blockIdx.y * VSTRIP;
    const int b  = blockIdx.z;
    const size_t plane = (size_t)HH * WW;
    const float2* tb = tin + (size_t)b * plane;
    const float*  mb = mag + (size_t)b * plane;

    float w0a[VSTRIP + 10], w1a[VSTRIP + 10], wea[VSTRIP + 10];
    #pragma unroll
    for (int j = 0; j < 10; ++j) {              // rows r0-5 .. r0+4 (g<HH always)
        int g = r0 - MU + j;
        float2 v = make_float2(0.f, 0.f); float mr = 0.f;
        if (g >= 0) { v = tb[(size_t)g * WW + c]; mr = mb[(size_t)g * WW + c]; }
        w0a[j] = v.x; w1a[j] = v.y; wea[j] = __expf(-s2 * mr);
    }
    #pragma unroll
    for (int i = 0; i < VSTRIP; ++i) {
        int g = r0 + i + MU;                    // g>=5 always; guard bottom only
        float2 v = make_float2(0.f, 0.f); float mr = 0.f;
        if (g < HH) { v = tb[(size_t)g * WW + c]; mr = mb[(size_t)g * WW + c]; }
        w0a[i + 10] = v.x; w1a[i + 10] = v.y; wea[i + 10] = __expf(-s2 * mr);

        float tx0 = w0a[i + MU], tx1 = w1a[i + MU];
        float remx = fast_rcp(wea[i + MU]);
        float a0 = 0.f, a1 = 0.f;
        #pragma unroll
        for (int d = 0; d <= 2 * MU; ++d) {
            float s = fast_rcp(fmaf(wea[i + d], remx, 1.f));   // (tanh(my-mx)+1)/2
            float w = s * fmaf(tx0, w0a[i + d], tx1 * w1a[i + d]);
            a0 = fmaf(w0a[i + d], w, a0);
            a1 = fmaf(w1a[i + d], w, a1);
        }
        float n2 = fmaf(a0, a0, a1 * a1);
        float inv = (n2 == 0.f) ? 1.f : fast_rsq(n2);
        tout[(size_t)b * plane + (size_t)(r0 + i) * WW + c] = make_float2(a0 * inv, a1 * inv);
    }
}

// ---------------------------------------------------------------------------
// Kernel 3: HORIZONTAL pass. Stage 32x80 (8-col halo; tang float2 stride 81,
// em stride 83 — conflict-free), window compute with lane<->row map, results
// ROUND-TRIP THROUGH LDS so global stores are lane-along-columns coalesced
// (R8's direct scattered-row stores were the hidden ~13us/pass bug).
// LDS 31360 B -> 5 blocks/CU.
// ---------------------------------------------------------------------------
template <int PLANAR_OUT>
__global__ __launch_bounds__(256) void etf_h(
    const float2* __restrict__ tin, float* __restrict__ tout,
    const float* __restrict__ mag, const float* __restrict__ block_max)
{
    __shared__ __align__(16) char smem[31360];
    __shared__ float smax[4];
    float2 (*sT)[81] = (float2(*)[81])smem;          // 32 x 81 float2 = 20736 B
    float* sE  = (float*)(smem + 20736);             // 32 x 83 floats  = 10624 B
    float* sv0 = (float*)smem;                       // results plane 0 (aliases sT)
    float* sv1 = (float*)smem + 32 * 81;             // results plane 1

    const int t = threadIdx.x;
    const float s2 = gmax_prologue(block_max, t, smax);

    const int w0 = blockIdx.x * 64;
    const int h0 = blockIdx.y * 32;
    const int b = blockIdx.z;
    const size_t plane = (size_t)HH * WW;
    const float2* tb = tin + (size_t)b * plane;
    const float*  mb = mag + (size_t)b * plane;

    // stage: tang 32x40 float4 (2px) chunks; em 32x20 float4 (4px) + exp
    for (int i = t; i < 1920; i += 256) {
        if (i < 1280) {
            int r = i / 40, c4 = i % 40;
            int gw = w0 - 8 + 2 * c4;
            float4 v = make_float4(0.f, 0.f, 0.f, 0.f);
            if (gw >= 0 && gw < WW)
                v = *(const float4*)(tb + (size_t)(h0 + r) * WW + gw);
            sT[r][c4 * 2]     = make_float2(v.x, v.y);
            sT[r][c4 * 2 + 1] = make_float2(v.z, v.w);
        } else {
            int j = i - 1280;
            int r = j / 20, c4 = j % 20;
            int gw = w0 - 8 + 4 * c4;
            float4 v = make_float4(0.f, 0.f, 0.f, 0.f);   // mag=0 -> em=1
            if (gw >= 0 && gw < WW)
                v = *(const float4*)(mb + (size_t)(h0 + r) * WW + gw);
            float* dst = &sE[r * 83 + 4 * c4];
            dst[0] = __expf(-s2 * v.x);
            dst[1] = __expf(-s2 * v.y);
            dst[2] = __expf(-s2 * v.z);
            dst[3] = __expf(-s2 * v.w);
        }
    }
    __syncthreads();

    // window load: r = t&31 (row), cg = t>>5 (8-col group); strides 81/83 odd
    const int r  = t & 31;
    const int cg = t >> 5;
    const int cb = 8 + cg * 8;
    float h0a[18], h1a[18], hea[18];
    #pragma unroll
    for (int j = 0; j < 18; ++j) {               // staged cols 3..76
        float2 v = sT[r][cb - MU + j];
        h0a[j] = v.x; h1a[j] = v.y;
        hea[j] = sE[r * 83 + cb - MU + j];
    }
    __syncthreads();                              // sT reads done; alias safe

    #pragma unroll
    for (int k = 0; k < 8; ++k) {
        float tx0 = h0a[k + MU], tx1 = h1a[k + MU];
        float remx = fast_rcp(hea[k + MU]);
        float a0 = 0.f, a1 = 0.f;
        #pragma unroll
        for (int d = 0; d <= 2 * MU; ++d) {
            float s = fast_rcp(fmaf(hea[k + d], remx, 1.f));
            float w = s * fmaf(tx0, h0a[k + d], tx1 * h1a[k + d]);
            a0 = fmaf(h0a[k + d], w, a0);
            a1 = fmaf(h1a[k + d], w, a1);
        }
        float n2 = fmaf(a0, a0, a1 * a1);
        float inv = (n2 == 0.f) ? 1.f : fast_rsq(n2);
        sv0[r * 81 + cb + k] = a0 * inv;          // stride 81: conflict-free
        sv1[r * 81 + cb + k] = a1 * inv;
    }
    __syncthreads();

    // coalesced writeout (lanes along cols)
    #pragma unroll
    for (int m = 0; m < 8; ++m) {
        int px = t + 256 * m;
        int rr = px >> 6, cc = px & 63;
        float v0 = sv0[rr * 81 + 8 + cc];
        float v1 = sv1[rr * 81 + 8 + cc];
        size_t gi = (size_t)(h0 + rr) * WW + (w0 + cc);
        if (PLANAR_OUT) {
            tout[(size_t)(2 * b)     * plane + gi] = v0;
            tout[(size_t)(2 * b + 1) * plane + gi] = v1;
        } else {
            ((float2*)tout)[(size_t)b * plane + gi] = make_float2(v0, v1);
        }
    }
}

extern "C" void kernel_launch(void* const* d_in, const int* in_sizes, int n_in,
                              void* d_out, int out_size, void* d_ws, size_t ws_size,
                              hipStream_t stream)
{
    const float* x = (const float*)d_in[0];   // (2,1,1024,1024) fp32
    char* ws = (char*)d_ws;
    const size_t plane = (size_t)HH * WW;

    float2* tfA = (float2*)ws;                                          // 16 MB
    float2* tfB = (float2*)(ws + sizeof(float) * BB * 2 * plane);       // 16 MB
    float* mag  = (float*)(ws + sizeof(float) * BB * 4 * plane);        // 8 MB raw
    float* block_max = (float*)(ws + sizeof(float) * BB * 5 * plane);   // 1024 floats

    sobel_init<<<dim3(4, 128, BB), 256, 0, stream>>>(x, tfA, mag, block_max);

    dim3 gv(4, HH / VSTRIP, BB);     // 1024 blocks
    dim3 gh(WW / 64, HH / 32, BB);   // 1024 blocks
    etf_v<<<gv, 256, 0, stream>>>(tfA, tfB, mag, block_max);
    etf_h<0><<<gh, 256, 0, stream>>>(tfB, (float*)tfA, mag, block_max);
    etf_v<<<gv, 256, 0, stream>>>(tfA, tfB, mag, block_max);
    etf_h<0><<<gh, 256, 0, stream>>>(tfB, (float*)tfA, mag, block_max);
    etf_v<<<gv, 256, 0, stream>>>(tfA, tfB, mag, block_max);
    etf_h<1><<<gh, 256, 0, stream>>>(tfB, (float*)d_out, mag, block_max);
}